// Round 9
// baseline (241.785 us; speedup 1.0000x reference)
//
#include <hip/hip_runtime.h>

// ---------- types ----------
typedef unsigned short u16;
typedef __attribute__((ext_vector_type(4))) float f32x4;
typedef __attribute__((ext_vector_type(8))) short s16x8;
typedef __attribute__((ext_vector_type(8))) __bf16 bf16x8;
typedef __attribute__((ext_vector_type(4))) __bf16 bf16x4;
typedef __attribute__((ext_vector_type(4))) unsigned short u16x4;

#define LOG2E 1.44269504088896340736f

__device__ __forceinline__ u16 f2bf(float f) {
  unsigned u = __builtin_bit_cast(unsigned, f);
  u += 0x7fffu + ((u >> 16) & 1u);  // RNE
  return (u16)(u >> 16);
}

__device__ __forceinline__ f32x4 mfma16(s16x8 a, s16x8 b, f32x4 c) {
  return __builtin_amdgcn_mfma_f32_16x16x32_bf16(
      __builtin_bit_cast(bf16x8, a), __builtin_bit_cast(bf16x8, b), c, 0, 0, 0);
}

// XOR-swizzle mask for u16-indexed rows of 64 elems (128B): flips idx bits 3..5.
__device__ __forceinline__ int swzm(int row) {
  return (((row & 7) ^ ((row >> 3) & 7)) << 3);
}

// global -> LDS direct copy, 16B per lane. LDS dest must be uniform-base + lane*16.
#define GLOAD_LDS16(g, l)                                                      \
  __builtin_amdgcn_global_load_lds(                                            \
      (const __attribute__((address_space(1))) unsigned int*)(g),              \
      (__attribute__((address_space(3))) unsigned int*)(l), 16, 0, 0)

// ---------- cast x f32 -> bf16 (4 elems/thread, exact grid) ----------
__global__ __launch_bounds__(256) void k_cast_bf16(const float* __restrict__ in,
                                                   u16* __restrict__ out) {
  int i = (blockIdx.x * 256 + threadIdx.x) * 4;
  float4 v = *(const float4*)(in + i);
  u16x4 o = {f2bf(v.x), f2bf(v.y), f2bf(v.z), f2bf(v.w)};
  *(u16x4*)(out + i) = o;
}

// ---------- Wq/Wk/Wv [H,C,D] f32 -> Wt [3*H*D][C] bf16 (B^T layout) ----------
__global__ __launch_bounds__(256) void k_wqkv(const float* __restrict__ Wq,
                                              const float* __restrict__ Wk,
                                              const float* __restrict__ Wv,
                                              u16* __restrict__ Wt) {
  int z = blockIdx.y;  // 0..47
  int qkv = z >> 4, h = z & 15;
  const float* in = (qkv == 0 ? Wq : (qkv == 1 ? Wk : Wv)) + h * 1024 * 64;
  int c0 = blockIdx.x * 64;
  __shared__ float tile[64][65];
  int t = threadIdx.x;
  int rA = t >> 4, cA = (t & 15) * 4;
#pragma unroll
  for (int rr = 0; rr < 4; ++rr) {
    int c = rr * 16 + rA;
    float4 v = *(const float4*)(in + (c0 + c) * 64 + cA);
    tile[c][cA] = v.x; tile[c][cA + 1] = v.y; tile[c][cA + 2] = v.z; tile[c][cA + 3] = v.w;
  }
  __syncthreads();
  int obase = qkv * 1024 + h * 64;
#pragma unroll
  for (int rr = 0; rr < 4; ++rr) {
    int d = rr * 16 + rA;
    u16x4 o = {f2bf(tile[cA][d]), f2bf(tile[cA + 1][d]), f2bf(tile[cA + 2][d]),
               f2bf(tile[cA + 3][d])};
    *(u16x4*)(Wt + (obase + d) * 1024 + c0 + cA) = o;
  }
}

// ---------- Wp [1024][1024] f32 -> WpT [n][k] bf16 ----------
__global__ __launch_bounds__(256) void k_wp(const float* __restrict__ in,
                                            u16* __restrict__ out) {
  int r0 = blockIdx.y * 64, c0 = blockIdx.x * 64;
  __shared__ float tile[64][65];
  int t = threadIdx.x;
  int rA = t >> 4, cA = (t & 15) * 4;
#pragma unroll
  for (int rr = 0; rr < 4; ++rr) {
    int r = rr * 16 + rA;
    float4 v = *(const float4*)(in + (r0 + r) * 1024 + c0 + cA);
    tile[r][cA] = v.x; tile[r][cA + 1] = v.y; tile[r][cA + 2] = v.z; tile[r][cA + 3] = v.w;
  }
  __syncthreads();
#pragma unroll
  for (int rr = 0; rr < 4; ++rr) {
    int c = rr * 16 + rA;
    u16x4 o = {f2bf(tile[cA][c]), f2bf(tile[cA + 1][c]), f2bf(tile[cA + 2][c]),
               f2bf(tile[cA + 3][c])};
    *(u16x4*)(out + (c0 + c) * 1024 + r0 + cA) = o;
  }
}

// ---------- V-part of QKV -> Vtg[(b*16+h)*64+d][t] (global V^T) ----------
__global__ __launch_bounds__(256) void k_vt(const u16* __restrict__ QKV,
                                            u16* __restrict__ Vtg) {
  const int bh = blockIdx.y;  // b*16+h
  const int b = bh >> 4, h = bh & 15;
  const int t0 = blockIdx.x * 64;
  __shared__ u16 tile[64][65];
  const int tid = threadIdx.x;
  const int tr = tid >> 3, ch = tid & 7;
#pragma unroll
  for (int i = 0; i < 2; ++i) {
    int t = tr + i * 32;
    s16x8 v = *(const s16x8*)&QKV[(b * 2048 + t0 + t) * 3072 + 2048 + h * 64 + ch * 8];
#pragma unroll
    for (int j = 0; j < 8; ++j) tile[t][ch * 8 + j] = (u16)v[j];
  }
  __syncthreads();
#pragma unroll
  for (int i = 0; i < 2; ++i) {
    int d = tr + i * 32;
    s16x8 o;
#pragma unroll
    for (int j = 0; j < 8; ++j) o[j] = (short)tile[ch * 8 + j][d];
    *(s16x8*)&Vtg[(bh * 64 + d) * 2048 + t0 + ch * 8] = o;
  }
}

// ---------- GEMM: C[M,N] = A[M,K] @ Bt[N,K]^T  (bf16 in, f32 acc) ----------
// 128xBN tile, BK=64, 4 waves. 2-phase pipeline: stage(t+1) before compute(t).
template <int F32OUT, int BN>
__global__ __launch_bounds__(256) void gemm_bt(const u16* __restrict__ A,
                                               const u16* __restrict__ Bt,
                                               u16* __restrict__ Cb,
                                               float* __restrict__ Cf,
                                               const float* __restrict__ bias,
                                               int M, int N, int K) {
  constexpr int WRN = (BN == 128) ? 2 : 4;  // waves along M
  constexpr int WRS = 128 / WRN;            // wave row stride (64 or 32)
  constexpr int MB = WRS / 16;              // row frags per wave (4 or 2)
  __shared__ alignas(16) u16 As[2][128 * 64];
  __shared__ alignas(16) u16 Bs[2][BN * 64];
  const int tid = threadIdx.x;
  const int lane = tid & 63, w = tid >> 6;
  const int wr = (BN == 128) ? (w >> 1) : w;
  const int wc = (BN == 128) ? (w & 1) : 0;
  const int g = lane >> 4, c15 = lane & 15;
  const int nbk = N / BN;
  const int bm = blockIdx.x / nbk, bn = blockIdx.x % nbk;

  f32x4 acc[MB][4] = {};

  const int srow = tid >> 3;        // 0..31 (+ i*32)
  const u16* Ag = A + (bm * 128 + srow) * K + (tid & 7) * 8;
  const u16* Bg = Bt + (bn * BN + srow) * K + (tid & 7) * 8;
  const int lds_e = tid * 8;        // + i*2048

  auto stage = [&](int kt, int buf) {
#pragma unroll
    for (int i = 0; i < 4; ++i) GLOAD_LDS16(Ag + i * 32 * K + kt, &As[buf][lds_e + i * 2048]);
#pragma unroll
    for (int i = 0; i < BN / 32; ++i) GLOAD_LDS16(Bg + i * 32 * K + kt, &Bs[buf][lds_e + i * 2048]);
  };

  stage(0, 0);
  __syncthreads();

  const int nkt = K >> 6;
  for (int t = 0; t < nkt; ++t) {
    const int c = t & 1;
    if (t + 1 < nkt) stage((t + 1) << 6, c ^ 1);
#pragma unroll
    for (int kc = 0; kc < 2; ++kc) {
      s16x8 a[MB], b[4];
#pragma unroll
      for (int mb = 0; mb < MB; ++mb)
        a[mb] = *(const s16x8*)&As[c][(wr * WRS + mb * 16 + c15) * 64 + kc * 32 + g * 8];
#pragma unroll
      for (int nb = 0; nb < 4; ++nb)
        b[nb] = *(const s16x8*)&Bs[c][(wc * 64 + nb * 16 + c15) * 64 + kc * 32 + g * 8];
#pragma unroll
      for (int mb = 0; mb < MB; ++mb)
#pragma unroll
        for (int nb = 0; nb < 4; ++nb) acc[mb][nb] = mfma16(a[mb], b[nb], acc[mb][nb]);
    }
    __syncthreads();  // publishes buf c^1 (vmcnt drained here, hidden by compute)
  }
#pragma unroll
  for (int mb = 0; mb < MB; ++mb) {
#pragma unroll
    for (int nb = 0; nb < 4; ++nb) {
      int row0 = bm * 128 + wr * WRS + mb * 16 + g * 4;
      int col = bn * BN + wc * 64 + nb * 16 + c15;
#pragma unroll
      for (int r = 0; r < 4; ++r) {
        float v = acc[mb][nb][r];
        if (F32OUT)
          Cf[(row0 + r) * N + col] = v + bias[col];
        else
          Cb[(row0 + r) * N + col] = f2bf(v);
      }
    }
  }
}

// ---------- flash attention (2-tile ILP per wave) ----------
// QKV [4096][3072] bf16 (row = b*2048+t, col = qkv*1024 + h*64 + d)
// Vtg [(b*16+h)*64+d][2048] bf16 (global V^T) — writer order b*16+h!
// AO: torch-raw-reshape layout: AO[(2h+b)*131072 + t*64 + d]  (as [4096][1024])
// Grid: 512 blocks x 256 threads (4 waves). Each wave owns TWO independent
// 16-row q-tiles (32 q-rows) -> two independent softmax/PV chains per wave
// (ILP-2 hides shfl/exp2/LDS latency); kf/vf fragment reads shared by both.
// XCD swizzle: wgid=(bid&7)*64+(bid>>3).
__global__ __launch_bounds__(256, 2) void attn_fwd(const u16* __restrict__ QKV,
                                                   const u16* __restrict__ Vtg,
                                                   u16* __restrict__ AO) {
  __shared__ alignas(16) u16 Ks[2][64 * 64];   // [key][d] swizzled
  __shared__ alignas(16) u16 Vt[2][64 * 64];   // [d][key] swizzled
  __shared__ alignas(16) u16 Ps[4][32 * 64];   // per-wave P [q(2 tiles)][key] swizzled
  const int tid = threadIdx.x, lane = tid & 63, w = tid >> 6;
  const int bid = blockIdx.x;
  const int wgid = (bid & 7) * 64 + (bid >> 3);  // bijective XCD clustering
  const int qb = wgid & 15;        // 0..15 (128 q-rows each)
  const int bh = wgid >> 4;        // 0..31 (= 2h+b, AO order)
  const int h = bh >> 1, b = bh & 1;
  const int g = lane >> 4, c15 = lane & 15;
  const int bt0 = b * 2048;
  const float CS = 0.125f * LOG2E;  // scale folded with log2e

  // Q fragments: tile ta rows = qb*128 + w*32 + ta*16 + c15
  s16x8 q[2][2];
#pragma unroll
  for (int ta = 0; ta < 2; ++ta)
#pragma unroll
    for (int kc = 0; kc < 2; ++kc) {
      int row = bt0 + qb * 128 + w * 32 + ta * 16 + c15;
      q[ta][kc] = *(const s16x8*)&QKV[row * 3072 + h * 64 + kc * 32 + g * 8];
    }

  f32x4 o[2][4] = {};
  float mrow[2] = {-1e30f, -1e30f}, lrow[2] = {0.f, 0.f};  // scaled domain

  // staging: 256 threads, 2 chunks of 16B each per K and per V tile
  const int srow = tid >> 3;        // 0..31 (+ i*32)
  const int sch = tid & 7;          // chunk 0..7

  auto stageKV = [&](int key0, int buf) {
#pragma unroll
    for (int i = 0; i < 2; ++i) {
      int row = srow + i * 32;
      int s7 = (row & 7) ^ ((row >> 3) & 7);
      const u16* ks =
          QKV + (bt0 + key0 + row) * 3072 + 1024 + h * 64 + ((sch ^ s7) * 8);
      GLOAD_LDS16(ks, &Ks[buf][tid * 8 + i * 2048]);
      const u16* vs =
          Vtg + ((b * 16 + h) * 64 + row) * 2048 + key0 + ((sch ^ s7) * 8);
      GLOAD_LDS16(vs, &Vt[buf][tid * 8 + i * 2048]);
    }
  };

  stageKV(0, 0);
  __syncthreads();

  for (int t = 0; t < 32; ++t) {
    const int c = t & 1;
    if (t < 31) stageKV((t + 1) * 64, c ^ 1);

    // S^T = K Q^T for both tiles: s[ta][nb] lane = S_raw[key=nb*16+g*4+r][q=c15]
    f32x4 s[2][4] = {};
    __builtin_amdgcn_s_setprio(1);
#pragma unroll
    for (int kc = 0; kc < 2; ++kc) {
      s16x8 kf[4];
#pragma unroll
      for (int nb = 0; nb < 4; ++nb) {
        int row = nb * 16 + c15;
        kf[nb] = *(const s16x8*)&Ks[c][row * 64 + ((kc * 32 + g * 8) ^ swzm(row))];
      }
#pragma unroll
      for (int ta = 0; ta < 2; ++ta)
#pragma unroll
        for (int nb = 0; nb < 4; ++nb)
          s[ta][nb] = mfma16(kf[nb], q[ta][kc], s[ta][nb]);
    }
    __builtin_amdgcn_s_setprio(0);

    // softmax: two independent chains (ILP-2)
    float mr[2];
#pragma unroll
    for (int ta = 0; ta < 2; ++ta) {
      float m01 = fmaxf(fmaxf(s[ta][0][0], s[ta][0][1]), fmaxf(s[ta][0][2], s[ta][0][3]));
      float m11 = fmaxf(fmaxf(s[ta][1][0], s[ta][1][1]), fmaxf(s[ta][1][2], s[ta][1][3]));
      float m21 = fmaxf(fmaxf(s[ta][2][0], s[ta][2][1]), fmaxf(s[ta][2][2], s[ta][2][3]));
      float m31 = fmaxf(fmaxf(s[ta][3][0], s[ta][3][1]), fmaxf(s[ta][3][2], s[ta][3][3]));
      float m0 = fmaxf(fmaxf(m01, m11), fmaxf(m21, m31));
      m0 = fmaxf(m0, __shfl_xor(m0, 16, 64));
      m0 = fmaxf(m0, __shfl_xor(m0, 32, 64));
      mr[ta] = m0 * CS;  // scaled-domain tile max
    }
    bool exceed = (mr[0] > mrow[0] + 8.0f) || (mr[1] > mrow[1] + 8.0f);
    if (__any(exceed)) {  // rescale (rare after warm-up)
#pragma unroll
      for (int ta = 0; ta < 2; ++ta) {
        float mn = fmaxf(mrow[ta], mr[ta]);
        float alpha = exp2f(mrow[ta] - mn);
        mrow[ta] = mn;
        lrow[ta] *= alpha;
#pragma unroll
        for (int r = 0; r < 4; ++r) {
          float aB = __shfl(alpha, g * 4 + r, 64);  // c15-domain -> row-domain
#pragma unroll
          for (int db = 0; db < 4; ++db) o[ta][db][r] *= aB;
        }
      }
    }
#pragma unroll
    for (int ta = 0; ta < 2; ++ta) {
      float m = mrow[ta];
#pragma unroll
      for (int nb = 0; nb < 4; ++nb)
#pragma unroll
        for (int r = 0; r < 4; ++r) s[ta][nb][r] = exp2f(fmaf(s[ta][nb][r], CS, -m));
      float s0 = (s[ta][0][0] + s[ta][0][1]) + (s[ta][0][2] + s[ta][0][3]);
      float s1 = (s[ta][1][0] + s[ta][1][1]) + (s[ta][1][2] + s[ta][1][3]);
      float s2 = (s[ta][2][0] + s[ta][2][1]) + (s[ta][2][2] + s[ta][2][3]);
      float s3 = (s[ta][3][0] + s[ta][3][1]) + (s[ta][3][2] + s[ta][3][3]);
      float rs = (s0 + s1) + (s2 + s3);
      rs += __shfl_xor(rs, 16, 64);
      rs += __shfl_xor(rs, 32, 64);
      lrow[ta] += rs;
      // P write: 4 consecutive keys (r=0..3) -> one b64 per nb (native cvt_pk)
      int row = ta * 16 + c15;
#pragma unroll
      for (int nb = 0; nb < 4; ++nb) {
        bf16x4 pk = {(__bf16)s[ta][nb][0], (__bf16)s[ta][nb][1],
                     (__bf16)s[ta][nb][2], (__bf16)s[ta][nb][3]};
        *(bf16x4*)&Ps[w][row * 64 + ((nb * 16 + g * 4) ^ swzm(row))] = pk;
      }
    }

    // O += P @ V for both tiles (vf shared)
    __builtin_amdgcn_s_setprio(1);
#pragma unroll
    for (int kc = 0; kc < 2; ++kc) {
      s16x8 pf[2], vf[4];
#pragma unroll
      for (int ta = 0; ta < 2; ++ta) {
        int row = ta * 16 + c15;
        pf[ta] = *(const s16x8*)&Ps[w][row * 64 + ((kc * 32 + g * 8) ^ swzm(row))];
      }
#pragma unroll
      for (int db = 0; db < 4; ++db) {
        int row = db * 16 + c15;
        vf[db] = *(const s16x8*)&Vt[c][row * 64 + ((kc * 32 + g * 8) ^ swzm(row))];
      }
#pragma unroll
      for (int ta = 0; ta < 2; ++ta)
#pragma unroll
        for (int db = 0; db < 4; ++db) o[ta][db] = mfma16(pf[ta], vf[db], o[ta][db]);
    }
    __builtin_amdgcn_s_setprio(0);

    __syncthreads();  // publishes buf c^1 (vmcnt drain hidden by compute)
  }

  // epilogue: O / l (broadcast lrow c15-domain -> row-domain), torch-raw layout
#pragma unroll
  for (int ta = 0; ta < 2; ++ta)
#pragma unroll
    for (int r = 0; r < 4; ++r) {
      float lB = __shfl(lrow[ta], g * 4 + r, 64);
      float rinv = 1.0f / lB;
      int trow = qb * 128 + w * 32 + ta * 16 + g * 4 + r;
#pragma unroll
      for (int db = 0; db < 4; ++db)
        AO[(2 * h + b) * 131072 + trow * 64 + db * 16 + c15] =
            __builtin_bit_cast(u16, (__bf16)(o[ta][db][r] * rinv));
    }
}

// ---------- launch ----------
extern "C" void kernel_launch(void* const* d_in, const int* in_sizes, int n_in,
                              void* d_out, int out_size, void* d_ws, size_t ws_size,
                              hipStream_t stream) {
  const float* x = (const float*)d_in[0];
  const float* Wq = (const float*)d_in[1];
  const float* Wk = (const float*)d_in[2];
  const float* Wv = (const float*)d_in[3];
  const float* Wp = (const float*)d_in[4];
  const float* bp = (const float*)d_in[5];
  float* out = (float*)d_out;

  u16* Xb = (u16*)d_ws;                   // [4096][1024]  (reused as Vtg later)
  u16* Wt = Xb + 4096 * 1024;             // [3072][1024]
  u16* WpT = Wt + 3072 * 1024;            // [1024][1024]
  u16* QKV = WpT + 1024 * 1024;           // [4096][3072]
  u16* AO = QKV + 4096 * 3072;            // [4096][1024]
  u16* Vtg = Xb;                          // [32*64][2048] — Xb dead after gemm1

  k_cast_bf16<<<4096, 256, 0, stream>>>(x, Xb);
  k_wqkv<<<dim3(16, 48), 256, 0, stream>>>(Wq, Wk, Wv, Wt);
  k_wp<<<dim3(16, 16), 256, 0, stream>>>(Wp, WpT);
  gemm_bt<0, 128><<<dim3(32 * 24), 256, 0, stream>>>(Xb, Wt, QKV, nullptr, nullptr, 4096, 3072, 1024);
  k_vt<<<dim3(32, 32), 256, 0, stream>>>(QKV, Vtg);
  attn_fwd<<<512, 256, 0, stream>>>(QKV, Vtg, AO);
  gemm_bt<1, 64><<<dim3(32 * 16), 256, 0, stream>>>(AO, WpT, nullptr, out, bp, 4096, 1024, 1024);
}